// Round 3
// baseline (679.653 us; speedup 1.0000x reference)
//
#include <hip/hip_runtime.h>
#include <math.h>

#define NN 100000
#define NEDGE 1600000
#define NTOT 1700000          // edges + self loops
#define FIN 512
#define NH1 8
#define NC1 8
#define F1 64                 // NH1*NC1
#define NC2 10
#define SLOPE 0.2f
#define EPSF 1e-16f
#define SCAN_BLK 1024
#define NB ((NN + SCAN_BLK - 1) / SCAN_BLK)   // 98

__device__ __forceinline__ float lrelu(float x) { return x > 0.f ? x : SLOPE * x; }
__device__ __forceinline__ float eluf(float x) { return x > 0.f ? x : __expf(x) - 1.f; }

__device__ __forceinline__ unsigned short f2bf_rne(float f) {
    unsigned int u = __float_as_uint(f);
    unsigned int r = (u + 0x7FFFu + ((u >> 16) & 1u)) >> 16;
    return (unsigned short)r;
}
__device__ __forceinline__ float bf2f(unsigned short b) {
    return __uint_as_float(((unsigned int)b) << 16);
}

// ---------------- GEMM1: 256x64 tile, 8x8 micro-tile, fused al/ar + bf16 h1 ----------------
#define GBM 256
#define GBK 32
#define AS_STRIDE 260   // 256+4: float4-aligned, spreads staging banks

__global__ __launch_bounds__(256) void k_gemm1(const float* __restrict__ x,
                                               const float* __restrict__ W,
                                               const float* __restrict__ asrc,
                                               const float* __restrict__ adst,
                                               unsigned short* __restrict__ h1b,
                                               float* __restrict__ al,
                                               float* __restrict__ ar)
{
    __shared__ float As[GBK][AS_STRIDE];
    __shared__ float Bs[GBK][F1];
    __shared__ float sas[F1], sad[F1];
    const int tid = threadIdx.x;
    const int row0 = blockIdx.x * GBM;
    const int ti = tid >> 3;          // 0..31 : row group (8 rows)
    const int tj = tid & 7;           // 0..7  : head (8 cols)
    const int ti8 = ti << 3, tj8 = tj << 3;
    if (tid < F1) { sas[tid] = asrc[tid]; sad[tid] = adst[tid]; }
    float acc[8][8] = {};

    for (int k0 = 0; k0 < FIN; k0 += GBK) {
        // stage x tile: 256 rows x 32 k = 2048 float4, transposed into As[k][row]
        #pragma unroll
        for (int l = 0; l < 8; ++l) {
            int idx = tid + l * 256;
            int r = idx >> 3, c4 = idx & 7;
            int gr = row0 + r;
            float4 v = make_float4(0.f, 0.f, 0.f, 0.f);
            if (gr < NN) v = *(const float4*)(x + (size_t)gr * FIN + k0 + (c4 << 2));
            As[(c4 << 2) + 0][r] = v.x;
            As[(c4 << 2) + 1][r] = v.y;
            As[(c4 << 2) + 2][r] = v.z;
            As[(c4 << 2) + 3][r] = v.w;
        }
        // stage W tile: 32 k x 64 n = 512 float4
        #pragma unroll
        for (int l = 0; l < 2; ++l) {
            int idx = tid + l * 256;
            int r = idx >> 4, c4 = idx & 15;
            *(float4*)&Bs[r][c4 << 2] = *(const float4*)(W + (size_t)(k0 + r) * F1 + (c4 << 2));
        }
        __syncthreads();
        #pragma unroll
        for (int kk = 0; kk < GBK; ++kk) {
            float4 a0 = *(const float4*)&As[kk][ti8];
            float4 a1 = *(const float4*)&As[kk][ti8 + 4];
            float4 b0 = *(const float4*)&Bs[kk][tj8];
            float4 b1 = *(const float4*)&Bs[kk][tj8 + 4];
            float a[8] = {a0.x, a0.y, a0.z, a0.w, a1.x, a1.y, a1.z, a1.w};
            float b[8] = {b0.x, b0.y, b0.z, b0.w, b1.x, b1.y, b1.z, b1.w};
            #pragma unroll
            for (int i = 0; i < 8; ++i)
                #pragma unroll
                for (int j = 0; j < 8; ++j)
                    acc[i][j] += a[i] * b[j];
        }
        __syncthreads();
    }
    // epilogue: bf16 h1 + fused al/ar (this thread owns head tj for its 8 rows)
    #pragma unroll
    for (int i = 0; i < 8; ++i) {
        int gr = row0 + ti8 + i;
        if (gr >= NN) break;
        float av = 0.f, dv = 0.f;
        unsigned short u[8];
        #pragma unroll
        for (int c = 0; c < 8; ++c) {
            av += acc[i][c] * sas[tj8 + c];
            dv += acc[i][c] * sad[tj8 + c];
            u[c] = f2bf_rne(acc[i][c]);
        }
        al[gr * NH1 + tj] = av;
        ar[gr * NH1 + tj] = dv;
        *(uint4*)(h1b + (size_t)gr * F1 + tj8) = *(uint4*)u;
    }
}

// ---------------- CSR build ----------------
__global__ void k_init1(int* __restrict__ cnt)
{
    int i = blockIdx.x * blockDim.x + threadIdx.x;
    if (i < NN) cnt[i] = 1;             // self-loop pre-counted (slot 0)
}

__global__ void k_hist(const int* __restrict__ ei, int* __restrict__ cnt,
                       int* __restrict__ pos)
{
    int e = blockIdx.x * blockDim.x + threadIdx.x;
    if (e >= NEDGE) return;
    pos[e] = atomicAdd(&cnt[ei[NEDGE + e]], 1);   // returns >=1 (slot 0 = self)
}

__global__ __launch_bounds__(256) void k_scan1(const int* __restrict__ cnt,
                                               int* __restrict__ off,
                                               int* __restrict__ bsum)
{
    __shared__ int s[256];
    int t = threadIdx.x;
    int base = blockIdx.x * SCAN_BLK + t * 4;
    int c0 = (base + 0 < NN) ? cnt[base + 0] : 0;
    int c1 = (base + 1 < NN) ? cnt[base + 1] : 0;
    int c2 = (base + 2 < NN) ? cnt[base + 2] : 0;
    int c3 = (base + 3 < NN) ? cnt[base + 3] : 0;
    int ts = c0 + c1 + c2 + c3;
    s[t] = ts;
    __syncthreads();
    #pragma unroll
    for (int d = 1; d < 256; d <<= 1) {
        int v = (t >= d) ? s[t - d] : 0;
        __syncthreads();
        s[t] += v;
        __syncthreads();
    }
    int run = s[t] - ts;
    if (t == 255) bsum[blockIdx.x] = s[255];
    if (base + 0 < NN) off[base + 0] = run; run += c0;
    if (base + 1 < NN) off[base + 1] = run; run += c1;
    if (base + 2 < NN) off[base + 2] = run; run += c2;
    if (base + 3 < NN) off[base + 3] = run;
}

__global__ void k_scan2(int* __restrict__ bsum, int* __restrict__ off)
{
    __shared__ int s[128];
    int t = threadIdx.x;                 // 128 threads
    int v = (t < NB) ? bsum[t] : 0;
    s[t] = v;
    __syncthreads();
    #pragma unroll
    for (int d = 1; d < 128; d <<= 1) {
        int w = (t >= d) ? s[t - d] : 0;
        __syncthreads();
        s[t] += w;
        __syncthreads();
    }
    if (t < NB) bsum[t] = s[t] - v;      // exclusive
    if (t == 0) off[NN] = NTOT;
}

// finalize offsets + drop self-loop src into slot 0
__global__ void k_scan3(int* __restrict__ off, const int* __restrict__ bsum,
                        int* __restrict__ esrc)
{
    int i = blockIdx.x * blockDim.x + threadIdx.x;
    if (i >= NN) return;
    int o = off[i] + bsum[i >> 10];
    off[i] = o;
    esrc[o] = i;
}

__global__ void k_scatter(const int* __restrict__ ei, const int* __restrict__ off,
                          const int* __restrict__ pos, int* __restrict__ esrc)
{
    int e = blockIdx.x * blockDim.x + threadIdx.x;
    if (e >= NEDGE) return;
    esrc[off[ei[NEDGE + e]] + pos[e]] = ei[e];
}

// ------------- agg1: one wave per dst node; fused softmax-agg + bias + ELU -------------
__global__ __launch_bounds__(256) void k_agg1csr(const int* __restrict__ off,
                                                 const int* __restrict__ esrc,
                                                 const float* __restrict__ al,
                                                 const float* __restrict__ ar,
                                                 const unsigned short* __restrict__ h1b,
                                                 const float* __restrict__ b1,
                                                 float* __restrict__ g)
{
    int node = blockIdx.x * 4 + (threadIdx.x >> 6);
    int lane = threadIdx.x & 63;
    int h = lane >> 3;
    int beg = off[node], end = off[node + 1];
    float arn = ar[node * NH1 + h];
    float acc0 = 0.f, acc1 = 0.f, ds0 = 0.f, ds1 = 0.f;
    int i = beg;
    for (; i + 1 < end; i += 2) {
        int s0 = esrc[i], s1 = esrc[i + 1];
        float e0 = __expf(lrelu(al[s0 * NH1 + h] + arn));
        float e1 = __expf(lrelu(al[s1 * NH1 + h] + arn));
        acc0 += bf2f(h1b[(size_t)s0 * F1 + lane]) * e0; ds0 += e0;
        acc1 += bf2f(h1b[(size_t)s1 * F1 + lane]) * e1; ds1 += e1;
    }
    if (i < end) {
        int s0 = esrc[i];
        float e0 = __expf(lrelu(al[s0 * NH1 + h] + arn));
        acc0 += bf2f(h1b[(size_t)s0 * F1 + lane]) * e0; ds0 += e0;
    }
    float v = (acc0 + acc1) / (ds0 + ds1 + EPSF);
    g[(size_t)node * F1 + lane] = eluf(v + b1[lane]);
}

// ------------- l2prep: h2 = g @ W2 ; al2/ar2 -------------
__global__ __launch_bounds__(256) void k_l2prep(
    const float* __restrict__ g, const float* __restrict__ W2,
    const float* __restrict__ asrc2, const float* __restrict__ adst2,
    float* __restrict__ h2, float* __restrict__ al2, float* __restrict__ ar2)
{
    __shared__ float sW[F1 * NC2];
    __shared__ float sas[NC2], sad[NC2];
    int tid = threadIdx.x;
    for (int i = tid; i < F1 * NC2; i += 256) sW[i] = W2[i];
    if (tid < NC2) { sas[tid] = asrc2[tid]; sad[tid] = adst2[tid]; }
    __syncthreads();
    int n = blockIdx.x * 256 + tid;
    if (n >= NN) return;

    const float* row = g + (size_t)n * F1;
    float acc[NC2] = {};
    #pragma unroll
    for (int c = 0; c < F1; c += 4) {
        float4 v = *(const float4*)(row + c);
        #pragma unroll
        for (int o = 0; o < NC2; ++o) {
            acc[o] += v.x * sW[(c + 0) * NC2 + o] + v.y * sW[(c + 1) * NC2 + o]
                    + v.z * sW[(c + 2) * NC2 + o] + v.w * sW[(c + 3) * NC2 + o];
        }
    }
    float sa = 0.f, sd = 0.f;
    #pragma unroll
    for (int o = 0; o < NC2; ++o) { sa += acc[o] * sas[o]; sd += acc[o] * sad[o]; }
    al2[n] = sa; ar2[n] = sd;
    float* h2p = h2 + (size_t)n * NC2;
    #pragma unroll
    for (int o = 0; o < NC2; ++o) h2p[o] = acc[o];
}

// ------------- agg2: 16-lane group per node; fused bias + log_softmax -------------
__global__ __launch_bounds__(256) void k_agg2csr(const int* __restrict__ off,
                                                 const int* __restrict__ esrc,
                                                 const float* __restrict__ al2,
                                                 const float* __restrict__ ar2,
                                                 const float* __restrict__ h2,
                                                 const float* __restrict__ b2,
                                                 float* __restrict__ out)
{
    int node = blockIdx.x * 16 + (threadIdx.x >> 4);
    int li = threadIdx.x & 15;
    int beg = off[node], end = off[node + 1];
    float arn = ar2[node];
    float acc = 0.f, dsum = 0.f;
    for (int i = beg; i < end; ++i) {
        int s = esrc[i];
        float ev = __expf(lrelu(al2[s] + arn));
        if (li < NC2) acc += h2[(size_t)s * NC2 + li] * ev;
        dsum += ev;
    }
    float z = (li < NC2) ? acc / (dsum + EPSF) + b2[li] : -1e30f;
    float m = z;
    #pragma unroll
    for (int d = 8; d >= 1; d >>= 1) m = fmaxf(m, __shfl_xor(m, d, 16));
    float ex = (li < NC2) ? __expf(z - m) : 0.f;
    float ss = ex;
    #pragma unroll
    for (int d = 8; d >= 1; d >>= 1) ss += __shfl_xor(ss, d, 16);
    float ls = __logf(ss) + m;
    if (li < NC2) out[(size_t)node * NC2 + li] = z - ls;
}

extern "C" void kernel_launch(void* const* d_in, const int* in_sizes, int n_in,
                              void* d_out, int out_size, void* d_ws, size_t ws_size,
                              hipStream_t stream)
{
    const float* x    = (const float*)d_in[0];
    const int*   ei   = (const int*)d_in[1];
    const float* W1   = (const float*)d_in[2];
    const float* as1  = (const float*)d_in[3];
    const float* ad1  = (const float*)d_in[4];
    const float* b1   = (const float*)d_in[5];
    const float* W2   = (const float*)d_in[6];
    const float* as2  = (const float*)d_in[7];
    const float* ad2  = (const float*)d_in[8];
    const float* b2   = (const float*)d_in[9];
    float* out = (float*)d_out;

    char* ws = (char*)d_ws;
    unsigned short* h1b = (unsigned short*)ws;                 // NN*64 bf16 = 12.8MB
    float* al1 = (float*)(ws + (size_t)NN * F1 * 2);           // NN*8
    float* ar1 = al1 + (size_t)NN * NH1;                       // NN*8
    float* g   = ar1 + (size_t)NN * NH1;                       // NN*64
    int* cnt   = (int*)(g + (size_t)NN * F1);                  // NN
    int* off   = cnt + NN;                                     // NN+1
    int* bsum  = off + NN + 1;                                 // 128
    int* esrc  = bsum + 128;                                   // NTOT
    int* pos   = esrc + NTOT;                                  // NEDGE
    float* h2  = (float*)(pos + NEDGE);                        // NN*10
    float* al2 = h2 + (size_t)NN * NC2;                        // NN
    float* ar2 = al2 + NN;                                     // NN

    k_gemm1<<<(NN + GBM - 1) / GBM, 256, 0, stream>>>(x, W1, as1, ad1, h1b, al1, ar1);
    k_init1<<<(NN + 255) / 256, 256, 0, stream>>>(cnt);
    k_hist<<<(NEDGE + 255) / 256, 256, 0, stream>>>(ei, cnt, pos);
    k_scan1<<<NB, 256, 0, stream>>>(cnt, off, bsum);
    k_scan2<<<1, 128, 0, stream>>>(bsum, off);
    k_scan3<<<(NN + 255) / 256, 256, 0, stream>>>(off, bsum, esrc);
    k_scatter<<<(NEDGE + 255) / 256, 256, 0, stream>>>(ei, off, pos, esrc);
    k_agg1csr<<<NN / 4, 256, 0, stream>>>(off, esrc, al1, ar1, h1b, b1, g);
    k_l2prep<<<(NN + 255) / 256, 256, 0, stream>>>(g, W2, as2, ad2, h2, al2, ar2);
    k_agg2csr<<<NN / 16, 256, 0, stream>>>(off, esrc, al2, ar2, h2, b2, out);
}

// Round 4
// 606.472 us; speedup vs baseline: 1.1207x; 1.1207x over previous
//
#include <hip/hip_runtime.h>
#include <math.h>

#define NN 100000
#define NEDGE 1600000
#define NTOT 1700000          // edges + self loops
#define FIN 512
#define NH1 8
#define NC1 8
#define F1 64                 // NH1*NC1
#define NC2 10
#define SLOPE 0.2f
#define EPSF 1e-16f
#define SCAN_BLK 1024
#define NB ((NN + SCAN_BLK - 1) / SCAN_BLK)   // 98

typedef short short8 __attribute__((ext_vector_type(8)));
typedef float f32x4 __attribute__((ext_vector_type(4)));

__device__ __forceinline__ float lrelu(float x) { return x > 0.f ? x : SLOPE * x; }
__device__ __forceinline__ float eluf(float x) { return x > 0.f ? x : __expf(x) - 1.f; }

__device__ __forceinline__ unsigned short f2bf_rne(float f) {
    unsigned int u = __float_as_uint(f);
    unsigned int r = (u + 0x7FFFu + ((u >> 16) & 1u)) >> 16;
    return (unsigned short)r;
}
__device__ __forceinline__ float bf2f(unsigned short b) {
    return __uint_as_float(((unsigned int)b) << 16);
}

// ---------------- init: cnt=1 (self-loop) + W1^T bf16 ----------------
__global__ void k_init(const float* __restrict__ W, unsigned short* __restrict__ wT,
                       int* __restrict__ cnt)
{
    int i = blockIdx.x * 256 + threadIdx.x;
    if (i < NN) cnt[i] = 1;
    if (i < F1 * FIN) {
        int n = i & 63, k = i >> 6;                 // consecutive threads: consecutive n (coalesced read)
        wT[n * FIN + k] = f2bf_rne(W[k * F1 + n]);
    }
}

// ---------------- GEMM1 (MFMA bf16): h1b[NN,64] = bf16(x) @ bf16(W1) ----------------
// 64-row tile, 4 waves x (16 rows x 64 cols), K-step 32. 1563 blocks.
#define LDA 40    // bf16 row stride (80 B): b128 frag reads land 2-way max (free)

__global__ __launch_bounds__(256) void k_gemm1(const float* __restrict__ x,
                                               const unsigned short* __restrict__ wT,
                                               unsigned short* __restrict__ h1b)
{
    __shared__ unsigned short Al[64][LDA];
    __shared__ unsigned short Bl[64][LDA];
    const int tid = threadIdx.x;
    const int row0 = blockIdx.x * 64;
    const int w  = tid >> 6;          // wave 0..3 -> rows 16w..16w+15
    const int l  = tid & 63;
    const int lr = l & 15;            // A row / B col within 16
    const int lg = l >> 4;            // k-group (8 contiguous k)
    f32x4 acc[4] = {};                // 4 col-tiles

    for (int k0 = 0; k0 < FIN; k0 += 32) {
        // stage A: 64 rows x 32 k, f32 -> bf16
        #pragma unroll
        for (int t2 = 0; t2 < 2; ++t2) {
            int idx = tid + t2 * 256;             // 0..511
            int r = idx >> 3, q = idx & 7;
            int gr = row0 + r;
            float4 v = (gr < NN) ? *(const float4*)(x + (size_t)gr * FIN + k0 + 4 * q)
                                 : make_float4(0.f, 0.f, 0.f, 0.f);
            ushort4 u;
            u.x = f2bf_rne(v.x); u.y = f2bf_rne(v.y);
            u.z = f2bf_rne(v.z); u.w = f2bf_rne(v.w);
            *(ushort4*)&Al[r][4 * q] = u;         // 8B-aligned (80r + 8q)
        }
        // stage B^T: 64 cols x 32 k bf16, straight 16B copies
        {
            int n = tid >> 2, q = tid & 3;
            *(uint4*)&Bl[n][8 * q] = *(const uint4*)(wT + (size_t)n * FIN + k0 + 8 * q);
        }
        __syncthreads();
        short8 a = *(const short8*)&Al[16 * w + lr][8 * lg];
        #pragma unroll
        for (int nt = 0; nt < 4; ++nt) {
            short8 b = *(const short8*)&Bl[16 * nt + lr][8 * lg];
            acc[nt] = __builtin_amdgcn_mfma_f32_16x16x32_bf16(a, b, acc[nt], 0, 0, 0);
        }
        __syncthreads();
    }
    // epilogue: D lane mapping col=l&15, row=4*(l>>4)+reg
    #pragma unroll
    for (int r = 0; r < 4; ++r) {
        int gr = row0 + 16 * w + 4 * lg + r;
        if (gr < NN) {
            #pragma unroll
            for (int nt = 0; nt < 4; ++nt)
                h1b[(size_t)gr * F1 + 16 * nt + lr] = f2bf_rne(acc[nt][r]);
        }
    }
}

// ---------------- prep1: al1/ar1 [NN,8] from bf16 h1 ----------------
__global__ void k_prep1(const unsigned short* __restrict__ h1b,
                        const float* __restrict__ asrc, const float* __restrict__ adst,
                        float* __restrict__ al, float* __restrict__ ar)
{
    int i = blockIdx.x * blockDim.x + threadIdx.x;
    if (i >= NN * NH1) return;
    int node = i >> 3, hh = i & 7;
    const unsigned short* hp = h1b + (size_t)node * F1 + hh * NC1;
    ushort4 u0 = *(const ushort4*)hp;
    ushort4 u1 = *(const ushort4*)(hp + 4);
    float hv[8] = {bf2f(u0.x), bf2f(u0.y), bf2f(u0.z), bf2f(u0.w),
                   bf2f(u1.x), bf2f(u1.y), bf2f(u1.z), bf2f(u1.w)};
    const float* as = asrc + hh * NC1;
    const float* ad = adst + hh * NC1;
    float sa = 0.f, sd = 0.f;
    #pragma unroll
    for (int c = 0; c < 8; ++c) { sa += hv[c] * as[c]; sd += hv[c] * ad[c]; }
    al[i] = sa; ar[i] = sd;
}

// ---------------- CSR build ----------------
__global__ void k_hist(const int* __restrict__ ei, int* __restrict__ cnt,
                       int* __restrict__ pos)
{
    int e = blockIdx.x * blockDim.x + threadIdx.x;
    if (e >= NEDGE) return;
    pos[e] = atomicAdd(&cnt[ei[NEDGE + e]], 1);   // >=1 (slot 0 = self-loop)
}

__global__ __launch_bounds__(256) void k_scan1(const int* __restrict__ cnt,
                                               int* __restrict__ off,
                                               int* __restrict__ bsum)
{
    __shared__ int s[256];
    int t = threadIdx.x;
    int base = blockIdx.x * SCAN_BLK + t * 4;
    int c0 = (base + 0 < NN) ? cnt[base + 0] : 0;
    int c1 = (base + 1 < NN) ? cnt[base + 1] : 0;
    int c2 = (base + 2 < NN) ? cnt[base + 2] : 0;
    int c3 = (base + 3 < NN) ? cnt[base + 3] : 0;
    int ts = c0 + c1 + c2 + c3;
    s[t] = ts;
    __syncthreads();
    #pragma unroll
    for (int d = 1; d < 256; d <<= 1) {
        int v = (t >= d) ? s[t - d] : 0;
        __syncthreads();
        s[t] += v;
        __syncthreads();
    }
    int run = s[t] - ts;
    if (t == 255) bsum[blockIdx.x] = s[255];
    if (base + 0 < NN) off[base + 0] = run; run += c0;
    if (base + 1 < NN) off[base + 1] = run; run += c1;
    if (base + 2 < NN) off[base + 2] = run; run += c2;
    if (base + 3 < NN) off[base + 3] = run;
}

__global__ void k_scan2(int* __restrict__ bsum, int* __restrict__ off)
{
    __shared__ int s[128];
    int t = threadIdx.x;
    int v = (t < NB) ? bsum[t] : 0;
    s[t] = v;
    __syncthreads();
    #pragma unroll
    for (int d = 1; d < 128; d <<= 1) {
        int w = (t >= d) ? s[t - d] : 0;
        __syncthreads();
        s[t] += w;
        __syncthreads();
    }
    if (t < NB) bsum[t] = s[t] - v;
    if (t == 0) off[NN] = NTOT;
}

__global__ void k_scan3(int* __restrict__ off, const int* __restrict__ bsum,
                        int* __restrict__ esrc)
{
    int i = blockIdx.x * blockDim.x + threadIdx.x;
    if (i >= NN) return;
    int o = off[i] + bsum[i >> 10];
    off[i] = o;
    esrc[o] = i;          // self-loop in slot 0
}

__global__ void k_scatter(const int* __restrict__ ei, const int* __restrict__ off,
                          const int* __restrict__ pos, int* __restrict__ esrc)
{
    int e = blockIdx.x * blockDim.x + threadIdx.x;
    if (e >= NEDGE) return;
    esrc[off[ei[NEDGE + e]] + pos[e]] = ei[e];
}

// ------------- agg1: one wave per dst node; fused softmax-agg + bias + ELU -------------
__global__ __launch_bounds__(256) void k_agg1csr(const int* __restrict__ off,
                                                 const int* __restrict__ esrc,
                                                 const float* __restrict__ al,
                                                 const float* __restrict__ ar,
                                                 const unsigned short* __restrict__ h1b,
                                                 const float* __restrict__ b1,
                                                 float* __restrict__ g)
{
    int node = blockIdx.x * 4 + (threadIdx.x >> 6);
    int lane = threadIdx.x & 63;
    int h = lane >> 3;
    int beg = off[node], end = off[node + 1];
    float arn = ar[node * NH1 + h];
    float acc0 = 0.f, acc1 = 0.f, ds0 = 0.f, ds1 = 0.f;
    int i = beg;
    for (; i + 1 < end; i += 2) {
        int s0 = esrc[i], s1 = esrc[i + 1];
        float e0 = __expf(lrelu(al[s0 * NH1 + h] + arn));
        float e1 = __expf(lrelu(al[s1 * NH1 + h] + arn));
        acc0 += bf2f(h1b[(size_t)s0 * F1 + lane]) * e0; ds0 += e0;
        acc1 += bf2f(h1b[(size_t)s1 * F1 + lane]) * e1; ds1 += e1;
    }
    if (i < end) {
        int s0 = esrc[i];
        float e0 = __expf(lrelu(al[s0 * NH1 + h] + arn));
        acc0 += bf2f(h1b[(size_t)s0 * F1 + lane]) * e0; ds0 += e0;
    }
    float v = (acc0 + acc1) / (ds0 + ds1 + EPSF);
    g[(size_t)node * F1 + lane] = eluf(v + b1[lane]);
}

// ------------- l2prep: packed[n][0..9]=h2, [10]=al2, [11]=ar2 -------------
__global__ __launch_bounds__(256) void k_l2prep(
    const float* __restrict__ g, const float* __restrict__ W2,
    const float* __restrict__ asrc2, const float* __restrict__ adst2,
    float* __restrict__ packed)
{
    __shared__ float sW[F1 * NC2];
    __shared__ float sas[NC2], sad[NC2];
    int tid = threadIdx.x;
    for (int i = tid; i < F1 * NC2; i += 256) sW[i] = W2[i];
    if (tid < NC2) { sas[tid] = asrc2[tid]; sad[tid] = adst2[tid]; }
    __syncthreads();
    int n = blockIdx.x * 256 + tid;
    if (n >= NN) return;

    const float* row = g + (size_t)n * F1;
    float acc[NC2] = {};
    #pragma unroll
    for (int c = 0; c < F1; c += 4) {
        float4 v = *(const float4*)(row + c);
        #pragma unroll
        for (int o = 0; o < NC2; ++o) {
            acc[o] += v.x * sW[(c + 0) * NC2 + o] + v.y * sW[(c + 1) * NC2 + o]
                    + v.z * sW[(c + 2) * NC2 + o] + v.w * sW[(c + 3) * NC2 + o];
        }
    }
    float sa = 0.f, sd = 0.f;
    #pragma unroll
    for (int o = 0; o < NC2; ++o) { sa += acc[o] * sas[o]; sd += acc[o] * sad[o]; }
    float* p = packed + (size_t)n * 12;
    #pragma unroll
    for (int o = 0; o < NC2; ++o) p[o] = acc[o];
    p[10] = sa; p[11] = sd;
}

// ------------- agg2: 16-lane group per node; one 48B gather/edge; fused log_softmax -------------
__global__ __launch_bounds__(256) void k_agg2csr(const int* __restrict__ off,
                                                 const int* __restrict__ esrc,
                                                 const float* __restrict__ packed,
                                                 const float* __restrict__ b2,
                                                 float* __restrict__ out)
{
    int node = blockIdx.x * 16 + (threadIdx.x >> 4);
    int li = threadIdx.x & 15;
    int beg = off[node], end = off[node + 1];
    float arn = packed[(size_t)node * 12 + 11];
    float acc = 0.f, dsum = 0.f;
    for (int i = beg; i < end; ++i) {
        int s = esrc[i];
        float val = (li < 12) ? packed[(size_t)s * 12 + li] : 0.f;
        float al2s = __shfl(val, 10, 16);
        float ev = __expf(lrelu(al2s + arn));
        if (li < NC2) acc += val * ev;
        dsum += ev;
    }
    float z = (li < NC2) ? acc / (dsum + EPSF) + b2[li] : -1e30f;
    float m = z;
    #pragma unroll
    for (int d = 8; d >= 1; d >>= 1) m = fmaxf(m, __shfl_xor(m, d, 16));
    float ex = (li < NC2) ? __expf(z - m) : 0.f;
    float ss = ex;
    #pragma unroll
    for (int d = 8; d >= 1; d >>= 1) ss += __shfl_xor(ss, d, 16);
    float ls = __logf(ss) + m;
    if (li < NC2) out[(size_t)node * NC2 + li] = z - ls;
}

extern "C" void kernel_launch(void* const* d_in, const int* in_sizes, int n_in,
                              void* d_out, int out_size, void* d_ws, size_t ws_size,
                              hipStream_t stream)
{
    const float* x    = (const float*)d_in[0];
    const int*   ei   = (const int*)d_in[1];
    const float* W1   = (const float*)d_in[2];
    const float* as1  = (const float*)d_in[3];
    const float* ad1  = (const float*)d_in[4];
    const float* b1   = (const float*)d_in[5];
    const float* W2   = (const float*)d_in[6];
    const float* as2  = (const float*)d_in[7];
    const float* ad2  = (const float*)d_in[8];
    const float* b2   = (const float*)d_in[9];
    float* out = (float*)d_out;

    char* ws = (char*)d_ws;
    unsigned short* h1b = (unsigned short*)ws;                     // NN*64 bf16
    unsigned short* wT  = h1b + (size_t)NN * F1;                   // 64*512 bf16
    float* al1 = (float*)(wT + (size_t)F1 * FIN);                  // NN*8
    float* ar1 = al1 + (size_t)NN * NH1;                           // NN*8
    float* g   = ar1 + (size_t)NN * NH1;                           // NN*64
    float* packed = g + (size_t)NN * F1;                           // NN*12
    int* cnt   = (int*)(packed + (size_t)NN * 12);                 // NN
    int* off   = cnt + NN;                                         // NN+1
    int* bsum  = off + NN + 1;                                     // 128
    int* esrc  = bsum + 128;                                       // NTOT
    int* pos   = esrc + NTOT;                                      // NEDGE

    k_init<<<(NN + 255) / 256, 256, 0, stream>>>(W1, wT, cnt);
    k_gemm1<<<(NN + 63) / 64, 256, 0, stream>>>(x, wT, h1b);
    k_hist<<<(NEDGE + 255) / 256, 256, 0, stream>>>(ei, cnt, pos);
    k_scan1<<<NB, 256, 0, stream>>>(cnt, off, bsum);
    k_scan2<<<1, 128, 0, stream>>>(bsum, off);
    k_scan3<<<(NN + 255) / 256, 256, 0, stream>>>(off, bsum, esrc);
    k_scatter<<<(NEDGE + 255) / 256, 256, 0, stream>>>(ei, off, pos, esrc);
    k_prep1<<<(NN * NH1 + 255) / 256, 256, 0, stream>>>(h1b, as1, ad1, al1, ar1);
    k_agg1csr<<<NN / 4, 256, 0, stream>>>(off, esrc, al1, ar1, h1b, b1, g);
    k_l2prep<<<(NN + 255) / 256, 256, 0, stream>>>(g, W2, as2, ad2, packed);
    k_agg2csr<<<NN / 16, 256, 0, stream>>>(off, esrc, packed, b2, out);
}

// Round 5
// 596.109 us; speedup vs baseline: 1.1401x; 1.0174x over previous
//
#include <hip/hip_runtime.h>
#include <math.h>

#define NN 100000
#define NEDGE 1600000
#define NTOT 1700000          // edges + self loops
#define FIN 512
#define NH1 8
#define NC1 8
#define F1 64                 // NH1*NC1
#define NC2 10
#define SLOPE 0.2f
#define EPSF 1e-16f
#define SCAN_BLK 1024
#define NB ((NN + SCAN_BLK - 1) / SCAN_BLK)   // 98

typedef short short8 __attribute__((ext_vector_type(8)));
typedef float f32x4 __attribute__((ext_vector_type(4)));

__device__ __forceinline__ float lrelu(float x) { return x > 0.f ? x : SLOPE * x; }
__device__ __forceinline__ float eluf(float x) { return x > 0.f ? x : __expf(x) - 1.f; }

__device__ __forceinline__ unsigned short f2bf_rne(float f) {
    unsigned int u = __float_as_uint(f);
    unsigned int r = (u + 0x7FFFu + ((u >> 16) & 1u)) >> 16;
    return (unsigned short)r;
}
__device__ __forceinline__ float bf2f(unsigned short b) {
    return __uint_as_float(((unsigned int)b) << 16);
}

// ---------------- init: cnt=1 (self-loop) + W1^T bf16 ----------------
__global__ void k_init(const float* __restrict__ W, unsigned short* __restrict__ wT,
                       int* __restrict__ cnt)
{
    int i = blockIdx.x * 256 + threadIdx.x;
    if (i < NN) cnt[i] = 1;
    if (i < F1 * FIN) {
        int n = i & 63, k = i >> 6;
        wT[n * FIN + k] = f2bf_rne(W[k * F1 + n]);
    }
}

// ---------------- GEMM1 (MFMA bf16) + fused al/ar epilogue ----------------
// 64-row tile, 4 waves x (16 rows x 64 cols), K-step 32. 1563 blocks.
#define LDA 40    // bf16 row stride (80 B)

__global__ __launch_bounds__(256) void k_gemm1(const float* __restrict__ x,
                                               const unsigned short* __restrict__ wT,
                                               const float* __restrict__ asrc,
                                               const float* __restrict__ adst,
                                               unsigned short* __restrict__ h1b,
                                               float* __restrict__ al,
                                               float* __restrict__ ar)
{
    __shared__ unsigned short Al[64][LDA];
    __shared__ unsigned short Bl[64][LDA];
    __shared__ float sas[F1], sad[F1];
    const int tid = threadIdx.x;
    const int row0 = blockIdx.x * 64;
    const int w  = tid >> 6;
    const int l  = tid & 63;
    const int lr = l & 15;
    const int lg = l >> 4;
    if (tid < F1) { sas[tid] = asrc[tid]; sad[tid] = adst[tid]; }
    f32x4 acc[4] = {};

    for (int k0 = 0; k0 < FIN; k0 += 32) {
        #pragma unroll
        for (int t2 = 0; t2 < 2; ++t2) {
            int idx = tid + t2 * 256;
            int r = idx >> 3, q = idx & 7;
            int gr = row0 + r;
            float4 v = (gr < NN) ? *(const float4*)(x + (size_t)gr * FIN + k0 + 4 * q)
                                 : make_float4(0.f, 0.f, 0.f, 0.f);
            ushort4 u;
            u.x = f2bf_rne(v.x); u.y = f2bf_rne(v.y);
            u.z = f2bf_rne(v.z); u.w = f2bf_rne(v.w);
            *(ushort4*)&Al[r][4 * q] = u;
        }
        {
            int n = tid >> 2, q = tid & 3;
            *(uint4*)&Bl[n][8 * q] = *(const uint4*)(wT + (size_t)n * FIN + k0 + 8 * q);
        }
        __syncthreads();
        short8 a = *(const short8*)&Al[16 * w + lr][8 * lg];
        #pragma unroll
        for (int nt = 0; nt < 4; ++nt) {
            short8 b = *(const short8*)&Bl[16 * nt + lr][8 * lg];
            acc[nt] = __builtin_amdgcn_mfma_f32_16x16x32_bf16(a, b, acc[nt], 0, 0, 0);
        }
        __syncthreads();
    }
    // h1b write: D lane mapping col=lr, row=4*lg+reg
    #pragma unroll
    for (int r = 0; r < 4; ++r) {
        int gr = row0 + 16 * w + 4 * lg + r;
        if (gr < NN) {
            #pragma unroll
            for (int nt = 0; nt < 4; ++nt)
                h1b[(size_t)gr * F1 + 16 * nt + lr] = f2bf_rne(acc[nt][r]);
        }
    }
    // fused al/ar: head = 2*nt + (lr>>3); reduce over the 8 lanes of lr&7
    float pa[4][4], pd[4][4];
    #pragma unroll
    for (int nt = 0; nt < 4; ++nt) {
        float wa = sas[16 * nt + lr], wd = sad[16 * nt + lr];
        #pragma unroll
        for (int r = 0; r < 4; ++r) {
            float c = acc[nt][r];
            pa[nt][r] = c * wa;
            pd[nt][r] = c * wd;
        }
    }
    #pragma unroll
    for (int d = 1; d <= 4; d <<= 1) {
        #pragma unroll
        for (int nt = 0; nt < 4; ++nt)
            #pragma unroll
            for (int r = 0; r < 4; ++r) {
                pa[nt][r] += __shfl_xor(pa[nt][r], d);
                pd[nt][r] += __shfl_xor(pd[nt][r], d);
            }
    }
    int low3 = lr & 7, hi = lr >> 3;
    if (low3 < 4) {
        int head = 2 * low3 + hi;
        #pragma unroll
        for (int nt = 0; nt < 4; ++nt) {
            if (low3 == nt) {       // compile-time index into pa/pd (no scratch)
                #pragma unroll
                for (int r = 0; r < 4; ++r) {
                    int gr = row0 + 16 * w + 4 * lg + r;
                    if (gr < NN) {
                        al[gr * NH1 + head] = pa[nt][r];
                        ar[gr * NH1 + head] = pd[nt][r];
                    }
                }
            }
        }
    }
}

// ---------------- CSR build ----------------
__global__ void k_hist(const int* __restrict__ ei, int* __restrict__ cnt,
                       int* __restrict__ pos)
{
    int e = blockIdx.x * blockDim.x + threadIdx.x;
    if (e >= NEDGE) return;
    pos[e] = atomicAdd(&cnt[ei[NEDGE + e]], 1);   // >=1 (slot 0 = self-loop)
}

__global__ __launch_bounds__(256) void k_scan1(const int* __restrict__ cnt,
                                               int* __restrict__ off,
                                               int* __restrict__ bsum)
{
    __shared__ int s[256];
    int t = threadIdx.x;
    int base = blockIdx.x * SCAN_BLK + t * 4;
    int c0 = (base + 0 < NN) ? cnt[base + 0] : 0;
    int c1 = (base + 1 < NN) ? cnt[base + 1] : 0;
    int c2 = (base + 2 < NN) ? cnt[base + 2] : 0;
    int c3 = (base + 3 < NN) ? cnt[base + 3] : 0;
    int ts = c0 + c1 + c2 + c3;
    s[t] = ts;
    __syncthreads();
    #pragma unroll
    for (int d = 1; d < 256; d <<= 1) {
        int v = (t >= d) ? s[t - d] : 0;
        __syncthreads();
        s[t] += v;
        __syncthreads();
    }
    int run = s[t] - ts;
    if (t == 255) bsum[blockIdx.x] = s[255];
    if (base + 0 < NN) off[base + 0] = run; run += c0;
    if (base + 1 < NN) off[base + 1] = run; run += c1;
    if (base + 2 < NN) off[base + 2] = run; run += c2;
    if (base + 3 < NN) off[base + 3] = run;
}

__global__ void k_scan2(int* __restrict__ bsum, int* __restrict__ off)
{
    __shared__ int s[128];
    int t = threadIdx.x;
    int v = (t < NB) ? bsum[t] : 0;
    s[t] = v;
    __syncthreads();
    #pragma unroll
    for (int d = 1; d < 128; d <<= 1) {
        int w = (t >= d) ? s[t - d] : 0;
        __syncthreads();
        s[t] += w;
        __syncthreads();
    }
    if (t < NB) bsum[t] = s[t] - v;
    if (t == 0) off[NN] = NTOT;
}

__global__ void k_scan3(int* __restrict__ off, const int* __restrict__ bsum,
                        int* __restrict__ esrc)
{
    int i = blockIdx.x * blockDim.x + threadIdx.x;
    if (i >= NN) return;
    int o = off[i] + bsum[i >> 10];
    off[i] = o;
    esrc[o] = i;          // self-loop in slot 0
}

__global__ void k_scatter(const int* __restrict__ ei, const int* __restrict__ off,
                          const int* __restrict__ pos, int* __restrict__ esrc)
{
    int e = blockIdx.x * blockDim.x + threadIdx.x;
    if (e >= NEDGE) return;
    esrc[off[ei[NEDGE + e]] + pos[e]] = ei[e];
}

// ------- agg1 (fused l2prep): wave per node -> packed[n][0..9]=h2,[10]=al2,[11]=ar2 -------
__global__ __launch_bounds__(256) void k_agg1(const int* __restrict__ off,
                                              const int* __restrict__ esrc,
                                              const float* __restrict__ al,
                                              const float* __restrict__ ar,
                                              const unsigned short* __restrict__ h1b,
                                              const float* __restrict__ b1,
                                              const float* __restrict__ W2,
                                              const float* __restrict__ as2,
                                              const float* __restrict__ ad2,
                                              float* __restrict__ packed)
{
    __shared__ float s2a[NC2], s2d[NC2];
    int tid = threadIdx.x;
    if (tid < NC2) { s2a[tid] = as2[tid]; s2d[tid] = ad2[tid]; }
    __syncthreads();
    int node = blockIdx.x * 4 + (tid >> 6);
    int lane = tid & 63;
    int h = lane >> 3;
    float b1l = b1[lane];
    float w2r[NC2];
    #pragma unroll
    for (int o = 0; o < NC2; ++o) w2r[o] = W2[lane * NC2 + o];

    int beg = off[node], end = off[node + 1];
    float arn = ar[node * NH1 + h];
    float a0 = 0.f, a1 = 0.f, a2 = 0.f, a3 = 0.f;
    float d0 = 0.f, d1 = 0.f, d2 = 0.f, d3 = 0.f;
    int i = beg;
    for (; i + 3 < end; i += 4) {
        int s0 = esrc[i], s1 = esrc[i + 1], s2 = esrc[i + 2], s3 = esrc[i + 3];
        float e0 = __expf(lrelu(al[s0 * NH1 + h] + arn));
        float e1 = __expf(lrelu(al[s1 * NH1 + h] + arn));
        float e2 = __expf(lrelu(al[s2 * NH1 + h] + arn));
        float e3 = __expf(lrelu(al[s3 * NH1 + h] + arn));
        a0 += bf2f(h1b[(size_t)s0 * F1 + lane]) * e0; d0 += e0;
        a1 += bf2f(h1b[(size_t)s1 * F1 + lane]) * e1; d1 += e1;
        a2 += bf2f(h1b[(size_t)s2 * F1 + lane]) * e2; d2 += e2;
        a3 += bf2f(h1b[(size_t)s3 * F1 + lane]) * e3; d3 += e3;
    }
    for (; i < end; ++i) {
        int s0 = esrc[i];
        float e0 = __expf(lrelu(al[s0 * NH1 + h] + arn));
        a0 += bf2f(h1b[(size_t)s0 * F1 + lane]) * e0; d0 += e0;
    }
    float v = ((a0 + a1) + (a2 + a3)) / (((d0 + d1) + (d2 + d3)) + EPSF);
    float gl = eluf(v + b1l);

    // fused h2 = g @ W2 via full-wave xor reduce (each lane owns one g feature)
    float p[NC2];
    #pragma unroll
    for (int o = 0; o < NC2; ++o) p[o] = gl * w2r[o];
    #pragma unroll
    for (int d = 1; d <= 32; d <<= 1)
        #pragma unroll
        for (int o = 0; o < NC2; ++o) p[o] += __shfl_xor(p[o], d);
    float sa = 0.f, sd = 0.f;
    #pragma unroll
    for (int o = 0; o < NC2; ++o) { sa += p[o] * s2a[o]; sd += p[o] * s2d[o]; }

    float* rec = packed + (size_t)node * 16;       // 64B-aligned record
    if (lane < NC2) rec[lane] = p[lane];
    if (lane == 10) rec[10] = sa;
    if (lane == 11) rec[11] = sd;
}

// ------------- agg2: 16-lane group per node; one 64B line/edge; fused log_softmax -------------
__global__ __launch_bounds__(256) void k_agg2(const int* __restrict__ off,
                                              const int* __restrict__ esrc,
                                              const float* __restrict__ packed,
                                              const float* __restrict__ b2,
                                              float* __restrict__ out)
{
    int node = blockIdx.x * 16 + (threadIdx.x >> 4);
    int li = threadIdx.x & 15;
    int beg = off[node], end = off[node + 1];
    float arn = packed[(size_t)node * 16 + 11];
    float acc = 0.f, acc1 = 0.f, dsum = 0.f, dsum1 = 0.f;
    int i = beg;
    for (; i + 1 < end; i += 2) {
        int s0 = esrc[i], s1 = esrc[i + 1];
        float v0 = (li < 12) ? packed[(size_t)s0 * 16 + li] : 0.f;
        float v1 = (li < 12) ? packed[(size_t)s1 * 16 + li] : 0.f;
        float al0 = __shfl(v0, 10, 16);
        float al1 = __shfl(v1, 10, 16);
        float e0 = __expf(lrelu(al0 + arn));
        float e1 = __expf(lrelu(al1 + arn));
        if (li < NC2) { acc += v0 * e0; acc1 += v1 * e1; }
        dsum += e0; dsum1 += e1;
    }
    if (i < end) {
        int s0 = esrc[i];
        float v0 = (li < 12) ? packed[(size_t)s0 * 16 + li] : 0.f;
        float al0 = __shfl(v0, 10, 16);
        float e0 = __expf(lrelu(al0 + arn));
        if (li < NC2) acc += v0 * e0;
        dsum += e0;
    }
    float z = (li < NC2) ? (acc + acc1) / (dsum + dsum1 + EPSF) + b2[li] : -1e30f;
    float m = z;
    #pragma unroll
    for (int d = 8; d >= 1; d >>= 1) m = fmaxf(m, __shfl_xor(m, d, 16));
    float ex = (li < NC2) ? __expf(z - m) : 0.f;
    float ss = ex;
    #pragma unroll
    for (int d = 8; d >= 1; d >>= 1) ss += __shfl_xor(ss, d, 16);
    float ls = __logf(ss) + m;
    if (li < NC2) out[(size_t)node * NC2 + li] = z - ls;
}

extern "C" void kernel_launch(void* const* d_in, const int* in_sizes, int n_in,
                              void* d_out, int out_size, void* d_ws, size_t ws_size,
                              hipStream_t stream)
{
    const float* x    = (const float*)d_in[0];
    const int*   ei   = (const int*)d_in[1];
    const float* W1   = (const float*)d_in[2];
    const float* as1  = (const float*)d_in[3];
    const float* ad1  = (const float*)d_in[4];
    const float* b1   = (const float*)d_in[5];
    const float* W2   = (const float*)d_in[6];
    const float* as2  = (const float*)d_in[7];
    const float* ad2  = (const float*)d_in[8];
    const float* b2   = (const float*)d_in[9];
    float* out = (float*)d_out;

    char* ws = (char*)d_ws;
    unsigned short* h1b = (unsigned short*)ws;                     // NN*64 bf16
    unsigned short* wT  = h1b + (size_t)NN * F1;                   // 64*512 bf16
    float* al1 = (float*)(wT + (size_t)F1 * FIN);                  // NN*8
    float* ar1 = al1 + (size_t)NN * NH1;                           // NN*8
    float* packed = ar1 + (size_t)NN * NH1;                        // NN*16 (64B recs)
    int* cnt   = (int*)(packed + (size_t)NN * 16);                 // NN
    int* off   = cnt + NN;                                         // NN+1
    int* bsum  = off + NN + 1;                                     // 128
    int* esrc  = bsum + 128;                                       // NTOT
    int* pos   = esrc + NTOT;                                      // NEDGE

    k_init<<<(NN + 255) / 256, 256, 0, stream>>>(W1, wT, cnt);
    k_gemm1<<<(NN + 63) / 64, 256, 0, stream>>>(x, wT, as1, ad1, h1b, al1, ar1);
    k_hist<<<(NEDGE + 255) / 256, 256, 0, stream>>>(ei, cnt, pos);
    k_scan1<<<NB, 256, 0, stream>>>(cnt, off, bsum);
    k_scan2<<<1, 128, 0, stream>>>(bsum, off);
    k_scan3<<<(NN + 255) / 256, 256, 0, stream>>>(off, bsum, esrc);
    k_scatter<<<(NEDGE + 255) / 256, 256, 0, stream>>>(ei, off, pos, esrc);
    k_agg1<<<NN / 4, 256, 0, stream>>>(off, esrc, al1, ar1, h1b, b1, W2, as2, ad2, packed);
    k_agg2<<<NN / 16, 256, 0, stream>>>(off, esrc, packed, b2, out);
}